// Round 4
// baseline (397.975 us; speedup 1.0000x reference)
//
#include <hip/hip_runtime.h>

#define B_   8
#define N_   1024
#define F0_  56
#define D_   70
#define DK_  96      // bf16 K-padded row stride (3 x 32)
#define DFC_ 128
#define NEG_BIG (-9e15f)

typedef __attribute__((ext_vector_type(8))) short bf16x8;
typedef __attribute__((ext_vector_type(4))) float f32x4;
typedef unsigned short ushortT;

__device__ __forceinline__ short f2bf(float x) {
  unsigned u = __builtin_bit_cast(unsigned, x);
  u += 0x7FFF + ((u >> 16) & 1);
  return (short)(u >> 16);
}
__device__ __forceinline__ float bfdec(unsigned u16bits) {
  unsigned v = u16bits << 16;
  return __builtin_bit_cast(float, v);
}

// ---------------------------------------------------------------- featem
__global__ __launch_bounds__(128) void featem_kernel(
    const float* __restrict__ H, const float* __restrict__ W, float* __restrict__ x)
{
  const int r = blockIdx.x, t = threadIdx.x;
  __shared__ float row[F0_];
  if (t < F0_) row[t] = H[(size_t)r * F0_ + t];
  __syncthreads();
  if (t < D_) {
    float a = 0.f;
#pragma unroll 8
    for (int m = 0; m < F0_; m++) a += row[m] * W[t * F0_ + m];
    x[(size_t)r * D_ + t] = a;
  }
}

// -------------------------------------------------- adjacency pre-pack
// u16: bits[15:1] = bf16(rbf+A1) with mantissa LSB dropped, bit0 = (A1>0)
__global__ __launch_bounds__(256) void prep_adj(
    const float* __restrict__ A1, const float* __restrict__ A2,
    const float* __restrict__ mup, const float* __restrict__ devp,
    ushortT* __restrict__ adjp)
{
  const size_t idx = ((size_t)blockIdx.x * 256 + threadIdx.x) * 4;
  const float4 a1 = *(const float4*)(A1 + idx);
  const float4 a2 = *(const float4*)(A2 + idx);
  const float mu = mup[0], idev = 1.0f / devp[0];
  ushortT out[4];
  const float a1v[4] = {a1.x, a1.y, a1.z, a1.w};
  const float a2v[4] = {a2.x, a2.y, a2.z, a2.w};
#pragma unroll
  for (int k = 0; k < 4; k++) {
    const float rbf = (a2v[k] <= 10.f) ? __expf(-(a2v[k] - mu) * (a2v[k] - mu) * idev) : 0.f;
    const float adj1 = rbf + a1v[k];
    ushortT u = ((ushortT)f2bf(adj1)) & 0xFFFE;
    if (a1v[k] > 0.f) u |= 1;
    out[k] = u;
  }
  *(uint2*)(adjp + idx) = *(uint2*)out;
}

// -------------------------------------------------- gating bitmasks from adjp
// word idx over [B*N][N/32]; bit j of m1b = adj value nonzero; m2b = A1 edge
__global__ __launch_bounds__(256) void mask_build(
    const ushortT* __restrict__ adjp, unsigned* __restrict__ m1b, unsigned* __restrict__ m2b)
{
  const size_t idx = (size_t)blockIdx.x * 256 + threadIdx.x;  // < B*N*32
  const ushortT* p = adjp + idx * 32;
  unsigned w1 = 0, w2 = 0;
#pragma unroll
  for (int k = 0; k < 32; k++) {
    const unsigned u = p[k];
    w1 |= ((u & 0xFFFEu) ? 1u : 0u) << k;
    w2 |= (u & 1u) << k;
  }
  m1b[idx] = w1; m2b[idx] = w2;
}

// ------------------------------------- fused h / hA / hT  (per 16 rows)
#define GROWS 16
__global__ __launch_bounds__(256) void gatmm_fused(
    const float* __restrict__ x, const float* __restrict__ W, const float* __restrict__ A,
    short* __restrict__ hb16, short* __restrict__ hAb16, short* __restrict__ hT)
{
  __shared__ float sW[D_ * D_];
  __shared__ float sA[D_ * D_];
  __shared__ float sx[GROWS * D_];
  __shared__ float sh[GROWS * D_];
  const int tid = threadIdx.x;
  const int r0 = blockIdx.x * GROWS;
  const int b = r0 >> 10, n0 = r0 & (N_ - 1);
  for (int i = tid; i < D_ * D_; i += 256) { sW[i] = W[i]; sA[i] = A[i]; }
  for (int i = tid; i < GROWS * D_; i += 256) sx[i] = x[(size_t)r0 * D_ + i];
  __syncthreads();
  for (int idx = tid; idx < GROWS * D_; idx += 256) {
    const int rr = idx / D_, d = idx - rr * D_;
    float a = 0.f;
#pragma unroll 7
    for (int m = 0; m < D_; m++) a += sx[rr * D_ + m] * sW[d * D_ + m];
    sh[idx] = a;
  }
  __syncthreads();
  for (int idx = tid; idx < GROWS * DK_; idx += 256) {
    const int rr = idx / DK_, d = idx - rr * DK_;
    const float v = (d < D_) ? sh[rr * D_ + d] : 0.f;
    const short u = f2bf(v);
    hb16[(size_t)(r0 + rr) * DK_ + d] = u;
    hT[((size_t)b * DK_ + d) * N_ + n0 + rr] = u;
  }
  for (int idx = tid; idx < GROWS * DK_; idx += 256) {
    const int rr = idx / DK_, d = idx - rr * DK_;
    float a = 0.f;
    if (d < D_) {
#pragma unroll 7
      for (int m = 0; m < D_; m++) a += sh[rr * D_ + m] * sA[m * D_ + d];
    }
    hAb16[(size_t)(r0 + rr) * DK_ + d] = f2bf(a);
  }
}

// ------------------------------------------- pass1: online softmax stats (MFMA)
template<bool PRE>
__global__ __launch_bounds__(256) void pass1_mfma(
    const unsigned* __restrict__ m1b, const unsigned* __restrict__ m2b,
    const short* __restrict__ hb16, const short* __restrict__ hAb16,
    const float* __restrict__ A1, const float* __restrict__ A2,
    const float* __restrict__ mup, const float* __restrict__ devp,
    float* __restrict__ M1p, float* __restrict__ S1p,
    float* __restrict__ M2p, float* __restrict__ S2p)
{
  const int jt = blockIdx.x, ic = blockIdx.y, b = blockIdx.z;
  const int tid = threadIdx.x, w = tid >> 6, lane = tid & 63;
  const int lr = lane & 15, kg = lane >> 4;
  const int ih = w >> 1, jh = w & 1;
  const int j0 = jt * 32;
  const short* hb  = hb16  + (size_t)b * N_ * DK_;
  const short* hAb = hAb16 + (size_t)b * N_ * DK_;

  bf16x8 b_h[3], b_hA[3];
  {
    const short* p = hb  + (size_t)(j0 + jh * 16 + lr) * DK_ + kg * 8;
    const short* q = hAb + (size_t)(j0 + jh * 16 + lr) * DK_ + kg * 8;
#pragma unroll
    for (int ks = 0; ks < 3; ks++) {
      b_h[ks]  = *(const bf16x8*)(p + ks * 32);
      b_hA[ks] = *(const bf16x8*)(q + ks * 32);
    }
  }
  const int jcol = j0 + jh * 16 + lr;
  float M1r = -3.0e38f, S1r = 0.f, M2r = -3.0e38f, S2r = 0.f;
  const int ibase = ic * (N_ / 4);
  float mu = 0.f, idev = 0.f;
  if (!PRE) { mu = mup[0]; idev = 1.0f / devp[0]; }
  const int bitp = jh * 16 + lr;

  for (int itl = 0; itl < N_ / 4; itl += 32) {
    const int i0 = ibase + itl + ih * 16;
    const short* pa = hAb + (size_t)(i0 + lr) * DK_ + kg * 8;
    const short* ph = hb  + (size_t)(i0 + lr) * DK_ + kg * 8;
    bf16x8 a_hA[3], a_h[3];
#pragma unroll
    for (int ks = 0; ks < 3; ks++) {
      a_hA[ks] = *(const bf16x8*)(pa + ks * 32);
      a_h[ks]  = *(const bf16x8*)(ph + ks * 32);
    }
    bool gon1[4], gon2[4];
    if constexpr (PRE) {
      const unsigned* W1p = m1b + ((size_t)b * N_ + i0 + kg * 4) * 32 + jt;
      const unsigned* W2p = m2b + ((size_t)b * N_ + i0 + kg * 4) * 32 + jt;
#pragma unroll
      for (int r = 0; r < 4; r++) {
        gon1[r] = (W1p[(size_t)r * 32] >> bitp) & 1u;
        gon2[r] = (W2p[(size_t)r * 32] >> bitp) & 1u;
      }
    } else {
      const float* A1p = A1 + ((size_t)b * N_ + i0 + kg * 4) * N_ + jcol;
      const float* A2p = A2 + ((size_t)b * N_ + i0 + kg * 4) * N_ + jcol;
#pragma unroll
      for (int r = 0; r < 4; r++) {
        const float a1 = A1p[(size_t)r * N_], a2 = A2p[(size_t)r * N_];
        gon1[r] = (a2 <= 10.f) || (a1 > 0.f); gon2[r] = a1 > 0.f;
      }
    }
    f32x4 E = {0.f, 0.f, 0.f, 0.f};
#pragma unroll
    for (int ks = 0; ks < 3; ks++)
      E = __builtin_amdgcn_mfma_f32_16x16x32_bf16(a_hA[ks], b_h[ks], E, 0, 0, 0);
#pragma unroll
    for (int ks = 0; ks < 3; ks++)
      E = __builtin_amdgcn_mfma_f32_16x16x32_bf16(a_h[ks], b_hA[ks], E, 0, 0, 0);
    // tile-local max/sum then one merge (short exp chain)
    {
      float mt = NEG_BIG;
#pragma unroll
      for (int r = 0; r < 4; r++) mt = gon1[r] ? fmaxf(mt, E[r]) : mt;
      float st = 0.f;
#pragma unroll
      for (int r = 0; r < 4; r++) st += gon1[r] ? __expf(E[r] - mt) : 0.f;
      const float nM = fmaxf(M1r, mt);
      S1r = S1r * __expf(M1r - nM) + st * __expf(mt - nM); M1r = nM;
    }
    {
      float mt = NEG_BIG;
#pragma unroll
      for (int r = 0; r < 4; r++) mt = gon2[r] ? fmaxf(mt, E[r]) : mt;
      float st = 0.f;
#pragma unroll
      for (int r = 0; r < 4; r++) st += gon2[r] ? __expf(E[r] - mt) : 0.f;
      const float nM = fmaxf(M2r, mt);
      S2r = S2r * __expf(M2r - nM) + st * __expf(mt - nM); M2r = nM;
    }
  }
#pragma unroll
  for (int off = 16; off <= 32; off <<= 1) {
    float Mo = __shfl_xor(M1r, off), So = __shfl_xor(S1r, off);
    float nM = fmaxf(M1r, Mo);
    S1r = S1r * __expf(M1r - nM) + So * __expf(Mo - nM); M1r = nM;
    Mo = __shfl_xor(M2r, off); So = __shfl_xor(S2r, off);
    nM = fmaxf(M2r, Mo);
    S2r = S2r * __expf(M2r - nM) + So * __expf(Mo - nM); M2r = nM;
  }
  __shared__ float sM[2][4][16], sS[2][4][16];
  if (lane < 16) {
    sM[0][w][lr] = M1r; sS[0][w][lr] = S1r;
    sM[1][w][lr] = M2r; sS[1][w][lr] = S2r;
  }
  __syncthreads();
  if (tid < 32) {
    const int jhh = tid >> 4, l2 = tid & 15;
    const size_t o = ((size_t)b * 4 + ic) * N_ + j0 + jhh * 16 + l2;
    {
      float Ma = sM[0][jhh][l2], Sa = sS[0][jhh][l2];
      float Mb = sM[0][2 + jhh][l2], Sb = sS[0][2 + jhh][l2];
      float nM = fmaxf(Ma, Mb);
      M1p[o] = nM; S1p[o] = Sa * __expf(Ma - nM) + Sb * __expf(Mb - nM);
    }
    {
      float Ma = sM[1][jhh][l2], Sa = sS[1][jhh][l2];
      float Mb = sM[1][2 + jhh][l2], Sb = sS[1][2 + jhh][l2];
      float nM = fmaxf(Ma, Mb);
      M2p[o] = nM; S2p[o] = Sa * __expf(Ma - nM) + Sb * __expf(Mb - nM);
    }
  }
}

// merge the 4 i-chunk partials
__global__ __launch_bounds__(256) void finalize_kernel(
    const float* __restrict__ M1p, const float* __restrict__ S1p,
    const float* __restrict__ M2p, const float* __restrict__ S2p,
    float* __restrict__ M1, float* __restrict__ S1,
    float* __restrict__ M2, float* __restrict__ S2)
{
  int idx = blockIdx.x * 256 + threadIdx.x;
  if (idx >= B_ * N_) return;
  int b = idx >> 10, k = idx & (N_ - 1);
  {
    float M = -3.0e38f, S = 0.f;
    for (int q = 0; q < 4; q++) {
      float m = M1p[((size_t)b * 4 + q) * N_ + k], s = S1p[((size_t)b * 4 + q) * N_ + k];
      float nM = fmaxf(M, m);
      S = S * __expf(M - nM) + s * __expf(m - nM); M = nM;
    }
    M1[idx] = M; S1[idx] = S;
  }
  {
    float M = -3.0e38f, S = 0.f;
    for (int q = 0; q < 4; q++) {
      float m = M2p[((size_t)b * 4 + q) * N_ + k], s = S2p[((size_t)b * 4 + q) * N_ + k];
      float nM = fmaxf(M, m);
      S = S * __expf(M - nM) + s * __expf(m - nM); M = nM;
    }
    M2[idx] = M; S2[idx] = S;
  }
}

// ------------------------------------------- pass2: E + PV via MFMA
template<bool PRE>
__global__ __launch_bounds__(256) void pass2_mfma(
    const ushortT* __restrict__ adjp,
    const short* __restrict__ hb16, const short* __restrict__ hAb16,
    const short* __restrict__ hT16,
    const float* __restrict__ A1, const float* __restrict__ A2,
    const float* __restrict__ mup, const float* __restrict__ devp,
    const float* __restrict__ M1, const float* __restrict__ S1,
    const float* __restrict__ M2, const float* __restrict__ S2,
    ushortT* __restrict__ hp1p, ushortT* __restrict__ hp2p, int njt)
{
  const int it = blockIdx.x, jc = blockIdx.y, b = blockIdx.z;
  const int tid = threadIdx.x, w = tid >> 6, lane = tid & 63;
  const int lr = lane & 15, kg = lane >> 4;
  const int ih = w >> 1, jh = w & 1;
  const int i0 = it * 32;
  const int dbase = (w & 1) * 3;

  const short* hb  = hb16  + (size_t)b * N_ * DK_;
  const short* hAb = hAb16 + (size_t)b * N_ * DK_;
  const short* hTb = hT16  + (size_t)b * DK_ * N_;

  bf16x8 a_hA[3], a_h[3];
  {
    const short* pa = hAb + (size_t)(i0 + ih * 16 + lr) * DK_ + kg * 8;
    const short* ph = hb  + (size_t)(i0 + ih * 16 + lr) * DK_ + kg * 8;
#pragma unroll
    for (int ks = 0; ks < 3; ks++) {
      a_hA[ks] = *(const bf16x8*)(pa + ks * 32);
      a_h[ks]  = *(const bf16x8*)(ph + ks * 32);
    }
  }
  float mu = 0.f, idev = 0.f;
  if (!PRE) { mu = mup[0]; idev = 1.0f / devp[0]; }
  f32x4 acc[2][3];
#pragma unroll
  for (int m = 0; m < 2; m++)
#pragma unroll
    for (int q = 0; q < 3; q++) acc[m][q] = (f32x4){0.f, 0.f, 0.f, 0.f};

  __shared__ short wlds[2][2][32][40];   // [parity][matrix][i][j], stride 40
  const int j0base = jc * njt * 32;

  for (int t = 0; t < njt; ++t) {
    const int j0 = j0base + t * 32;
    const int jcol = j0 + jh * 16 + lr;
    const int par = t & 1;
    // ---- issue all independent global loads up front
    bf16x8 b_h[3], b_hA[3], bt[3];
    {
      const short* p = hb  + (size_t)(j0 + jh * 16 + lr) * DK_ + kg * 8;
      const short* q = hAb + (size_t)(j0 + jh * 16 + lr) * DK_ + kg * 8;
#pragma unroll
      for (int ks = 0; ks < 3; ks++) {
        b_h[ks]  = *(const bf16x8*)(p + ks * 32);
        b_hA[ks] = *(const bf16x8*)(q + ks * 32);
      }
    }
#pragma unroll
    for (int q = 0; q < 3; q++)
      bt[q] = *(const bf16x8*)(hTb + (size_t)((dbase + q) * 16 + lr) * N_ + j0 + kg * 8);

    float adj1v[4]; bool gon1[4], gon2[4];
    if constexpr (PRE) {
      // adj is symmetric: read transposed row (contiguous in i) as one 8B load
      const ushortT* Ap = adjp + ((size_t)b * N_ + jcol) * N_ + i0 + ih * 16 + kg * 4;
      ushortT uu[4];
      *(uint2*)uu = *(const uint2*)Ap;
#pragma unroll
      for (int r = 0; r < 4; r++) {
        adj1v[r] = bfdec(uu[r] & 0xFFFEu);
        gon1[r] = (uu[r] & 0xFFFEu) != 0; gon2[r] = (uu[r] & 1u) != 0;
      }
    } else {
      const float* A1p = A1 + ((size_t)b * N_ + i0 + ih * 16 + kg * 4) * N_ + jcol;
      const float* A2p = A2 + ((size_t)b * N_ + i0 + ih * 16 + kg * 4) * N_ + jcol;
#pragma unroll
      for (int r = 0; r < 4; r++) {
        const float a1 = A1p[(size_t)r * N_], a2 = A2p[(size_t)r * N_];
        const float rbf = (a2 <= 10.f) ? __expf(-(a2 - mu) * (a2 - mu) * idev) : 0.f;
        adj1v[r] = rbf + a1;
        gon1[r] = adj1v[r] > 0.f; gon2[r] = a1 > 0.f;
      }
    }
    const float M1j = M1[(size_t)b * N_ + jcol];
    const float is1 = 1.0f / S1[(size_t)b * N_ + jcol];
    const float M2j = M2[(size_t)b * N_ + jcol];
    const float is2 = 1.0f / S2[(size_t)b * N_ + jcol];

    f32x4 E = {0.f, 0.f, 0.f, 0.f};
#pragma unroll
    for (int ks = 0; ks < 3; ks++)
      E = __builtin_amdgcn_mfma_f32_16x16x32_bf16(a_hA[ks], b_h[ks], E, 0, 0, 0);
#pragma unroll
    for (int ks = 0; ks < 3; ks++)
      E = __builtin_amdgcn_mfma_f32_16x16x32_bf16(a_h[ks], b_hA[ks], E, 0, 0, 0);

    short w1v[4], w2v[4];
#pragma unroll
    for (int r = 0; r < 4; r++) {
      const float e = E[r];
      w1v[r] = f2bf(gon1[r] ? __expf(e - M1j) * adj1v[r] * is1 : 0.f);
      w2v[r] = f2bf(gon2[r] ? __expf(e - M2j) * is2 : 0.f);
    }
#pragma unroll
    for (int r = 0; r < 4; r++) {
      wlds[par][0][ih * 16 + kg * 4 + r][jh * 16 + lr] = w1v[r];
      wlds[par][1][ih * 16 + kg * 4 + r][jh * 16 + lr] = w2v[r];
    }
    __syncthreads();
#pragma unroll
    for (int m = 0; m < 2; m++) {
      bf16x8 af = *(const bf16x8*)&wlds[par][m][ih * 16 + lr][kg * 8];
#pragma unroll
      for (int q = 0; q < 3; q++)
        acc[m][q] = __builtin_amdgcn_mfma_f32_16x16x32_bf16(af, bt[q], acc[m][q], 0, 0, 0);
    }
  }
#pragma unroll
  for (int m = 0; m < 2; m++) {
#pragma unroll
    for (int q = 0; q < 3; q++) {
      const int dt = dbase + q;
      if (dt < 5) {
        ushortT* dst = (m ? hp2p : hp1p) +
            (((size_t)jc * B_ + b) * N_ + i0 + ih * 16 + kg * 4) * 80 + dt * 16 + lr;
#pragma unroll
        for (int r = 0; r < 4; r++) dst[(size_t)r * 80] = (ushortT)f2bf(acc[m][q][r]);
      }
    }
  }
}

// ---------------------- gating + combine (+partial sum, relu), in-place x
__global__ __launch_bounds__(256) void combine_kernel(
    float* __restrict__ x,
    const ushortT* __restrict__ hp1p, const ushortT* __restrict__ hp2p, int JC,
    const float* __restrict__ g1, const float* __restrict__ g2w,
    const float* __restrict__ g2b)
{
  const int r = blockIdx.x * 4 + (threadIdx.x >> 6);
  const int t = threadIdx.x & 63;
  float s1a = 0.f, s2a = 0.f, s1b = 0.f, s2b = 0.f;
  for (int q = 0; q < JC; q++) {
    const size_t base = ((size_t)q * (B_ * N_) + r) * 80;
    s1a += bfdec(hp1p[base + t]);
    s2a += bfdec(hp2p[base + t]);
    if (t < D_ - 64) {
      s1b += bfdec(hp1p[base + 64 + t]);
      s2b += bfdec(hp2p[base + 64 + t]);
    }
  }
  const float a0 = fmaxf(s1a, 0.f), b0 = fmaxf(s2a, 0.f);
  const float a1v = fmaxf(s1b, 0.f), b1v = fmaxf(s2b, 0.f);
  float* xr = x + (size_t)r * D_;
  const float x0 = xr[t];
  float d1 = x0 * g1[t], d2 = a0 * g2w[t], d3 = b0 * g2w[t];
  float x1 = 0.f;
  if (t < D_ - 64) {
    x1 = xr[64 + t];
    d1 += x1 * g1[64 + t]; d2 += a1v * g2w[64 + t]; d3 += b1v * g2w[64 + t];
  }
#pragma unroll
  for (int off = 1; off < 64; off <<= 1) {
    d1 += __shfl_xor(d1, off);
    d2 += __shfl_xor(d2, off);
    d3 += __shfl_xor(d3, off);
  }
  const float bb = g2b[0];
  const float c1 = 1.f / (1.f + __expf(-(d1 + d2 + bb)));
  const float c2 = 1.f / (1.f + __expf(-(d1 + d3 + bb)));
  xr[t] = (c1 * x0 + (1.f - c1) * a0) - (c2 * x0 + (1.f - c2) * b0);
  if (t < D_ - 64)
    xr[64 + t] = (c1 * x1 + (1.f - c1) * a1v) - (c2 * x1 + (1.f - c2) * b1v);
}

// ------------------------------------------- masked sum pool over N
__global__ __launch_bounds__(256) void pool_kernel(
    const float* __restrict__ x, const float* __restrict__ V, float* __restrict__ pooled)
{
  const int d = blockIdx.x, b = blockIdx.y, t = threadIdx.x;
  const float* xb = x + (size_t)b * N_ * D_;
  const float* Vb = V + (size_t)b * N_;
  float s = 0.f;
  for (int n = t; n < N_; n += 256) s += xb[(size_t)n * D_ + d] * Vb[n];
#pragma unroll
  for (int off = 32; off >= 1; off >>= 1) s += __shfl_down(s, off);
  __shared__ float red[4];
  if ((t & 63) == 0) red[t >> 6] = s;
  __syncthreads();
  if (t == 0) pooled[b * D_ + d] = red[0] + red[1] + red[2] + red[3];
}

// ------------------------------------------- MLP head (single block, 1024 thr)
__global__ __launch_bounds__(1024) void fc_kernel(
    const float* __restrict__ pooled,
    const float* __restrict__ w0, const float* __restrict__ b0,
    const float* __restrict__ w1, const float* __restrict__ b1,
    const float* __restrict__ w2, const float* __restrict__ b2,
    const float* __restrict__ w3, const float* __restrict__ b3,
    float* __restrict__ out)
{
  __shared__ float pin[B_][D_];
  __shared__ float bufA[B_][DFC_], bufB[B_][DFC_];
  const int t = threadIdx.x;
  if (t < B_ * D_) pin[t / D_][t % D_] = pooled[t];
  __syncthreads();
  const int r = t >> 7, o = t & 127;
  // layer 0: [8,70] @ [70,128]^T  (w0 row stride 70 floats = 280B -> float2 ok)
  {
    float a = b0[o];
    const float2* wr = (const float2*)(w0 + o * D_);
#pragma unroll
    for (int m2 = 0; m2 < D_ / 2; m2++) {
      const float2 wv = wr[m2];
      a += pin[r][m2 * 2] * wv.x + pin[r][m2 * 2 + 1] * wv.y;
    }
    bufA[r][o] = fmaxf(a, 0.f);
  }
  __syncthreads();
  {
    float a = b1[o];
    const float4* wr = (const float4*)(w1 + o * DFC_);
    const float4* br = (const float4*)&bufA[r][0];
#pragma unroll
    for (int m4 = 0; m4 < DFC_ / 4; m4++) {
      const float4 wv = wr[m4], bv = br[m4];
      a += bv.x * wv.x + bv.y * wv.y + bv.z * wv.z + bv.w * wv.w;
    }
    bufB[r][o] = fmaxf(a, 0.f);
  }
  __syncthreads();
  {
    float a = b2[o];
    const float4* wr = (const float4*)(w2 + o * DFC_);
    const float4* br = (const float4*)&bufB[r][0];
#pragma unroll
    for (int m4 = 0; m4 < DFC_ / 4; m4++) {
      const float4 wv = wr[m4], bv = br[m4];
      a += bv.x * wv.x + bv.y * wv.y + bv.z * wv.z + bv.w * wv.w;
    }
    bufA[r][o] = fmaxf(a, 0.f);
  }
  __syncthreads();
  if (t < 64) {
    const int rr = t >> 3, l8 = t & 7;
    const float4* wr = (const float4*)(w3 + l8 * 16);
    const float4* br = (const float4*)&bufA[rr][l8 * 16];
    float a = 0.f;
#pragma unroll
    for (int m4 = 0; m4 < 4; m4++) {
      const float4 wv = wr[m4], bv = br[m4];
      a += bv.x * wv.x + bv.y * wv.y + bv.z * wv.z + bv.w * wv.w;
    }
    a += __shfl_xor(a, 1); a += __shfl_xor(a, 2); a += __shfl_xor(a, 4);
    if (l8 == 0) out[rr] = 1.f / (1.f + __expf(-(a + b3[0])));
  }
}

// ----------------------------------------------------------------------
extern "C" void kernel_launch(void* const* d_in, const int* in_sizes, int n_in,
                              void* d_out, int out_size, void* d_ws, size_t ws_size,
                              hipStream_t stream)
{
  const float* H     = (const float*)d_in[0];
  const float* A1    = (const float*)d_in[1];
  const float* A2    = (const float*)d_in[2];
  const float* V     = (const float*)d_in[3];
  const float* few   = (const float*)d_in[4];
  const float* mup   = (const float*)d_in[5];
  const float* devp  = (const float*)d_in[6];
  const float* gW    = (const float*)d_in[7];
  const float* gA    = (const float*)d_in[8];
  const float* g1    = (const float*)d_in[9];
  const float* g2w   = (const float*)d_in[10];
  const float* g2b   = (const float*)d_in[11];
  const float* w0 = (const float*)d_in[12]; const float* b0 = (const float*)d_in[13];
  const float* w1 = (const float*)d_in[14]; const float* b1 = (const float*)d_in[15];
  const float* w2 = (const float*)d_in[16]; const float* b2 = (const float*)d_in[17];
  const float* w3 = (const float*)d_in[18]; const float* b3 = (const float*)d_in[19];
  float* outp = (float*)d_out;

  float* ws = (float*)d_ws;
  // fixed layout (float offsets)
  float* x     = ws;                         // 573440
  short* hb16  = (short*)(ws + 573440);      // B*N*96 bf16
  short* hAb16 = (short*)(ws + 966656);
  short* hT16  = (short*)(ws + 1359872);     // B*96*N bf16
  float* M1  = ws + 1753088;
  float* S1  = ws + 1761280;
  float* M2  = ws + 1769472;
  float* S2  = ws + 1777664;
  float* M1p = ws + 1785856;
  float* S1p = ws + 1818624;
  float* M2p = ws + 1851392;
  float* S2p = ws + 1884160;
  float* pooled = ws + 1916928;              // 576 -> end 1917504
  ushortT* adjp = (ushortT*)(ws + 1917504);  // 8M u16 = 4194304 f (PRE only)
  unsigned* m1b = (unsigned*)(ws + 6111808); // 262144 u32
  unsigned* m2b = (unsigned*)(ws + 6373952); // 262144 u32  -> end 6636096

  auto need = [](bool pre, int jc) -> size_t {
    return (size_t)((pre ? 6636096u : 1917504u) + (size_t)jc * 655360u) * 4u;
  };
  bool PRE; int JC;
  if      (need(true, 4) <= ws_size) { PRE = true;  JC = 4; }
  else if (need(true, 2) <= ws_size) { PRE = true;  JC = 2; }
  else if (need(true, 1) <= ws_size) { PRE = true;  JC = 1; }
  else if (need(false,4) <= ws_size) { PRE = false; JC = 4; }
  else if (need(false,2) <= ws_size) { PRE = false; JC = 2; }
  else if (need(false,1) <= ws_size) { PRE = false; JC = 1; }
  else return;
  ushortT* hp1p = (ushortT*)(ws + (PRE ? 6636096u : 1917504u));
  ushortT* hp2p = hp1p + (size_t)JC * 655360u;
  const int njt = (N_ / 32) / JC;

  const int ROWS = B_ * N_;
  featem_kernel<<<ROWS, 128, 0, stream>>>(H, few, x);
  if (PRE) {
    prep_adj<<<(B_ * N_ * N_ / 4) / 256, 256, 0, stream>>>(A1, A2, mup, devp, adjp);
    mask_build<<<(B_ * N_ * 32) / 256, 256, 0, stream>>>(adjp, m1b, m2b);
  }

  for (int k = 0; k < 4; k++) {
    const float* Wk  = gW  + (size_t)k * D_ * D_;
    const float* Ak  = gA  + (size_t)k * D_ * D_;
    const float* g1k = g1  + (size_t)k * D_;
    const float* g2k = g2w + (size_t)k * D_;
    const float* gbk = g2b + k;
    gatmm_fused<<<ROWS / GROWS, 256, 0, stream>>>(x, Wk, Ak, hb16, hAb16, hT16);
    if (PRE)
      pass1_mfma<true><<<dim3(32, 4, B_), 256, 0, stream>>>(m1b, m2b, hb16, hAb16, A1, A2,
                                                            mup, devp, M1p, S1p, M2p, S2p);
    else
      pass1_mfma<false><<<dim3(32, 4, B_), 256, 0, stream>>>(m1b, m2b, hb16, hAb16, A1, A2,
                                                             mup, devp, M1p, S1p, M2p, S2p);
    finalize_kernel<<<(B_ * N_ + 255) / 256, 256, 0, stream>>>(M1p, S1p, M2p, S2p,
                                                               M1, S1, M2, S2);
    if (PRE)
      pass2_mfma<true><<<dim3(32, JC, B_), 256, 0, stream>>>(adjp, hb16, hAb16, hT16,
          A1, A2, mup, devp, M1, S1, M2, S2, hp1p, hp2p, njt);
    else
      pass2_mfma<false><<<dim3(32, JC, B_), 256, 0, stream>>>(adjp, hb16, hAb16, hT16,
          A1, A2, mup, devp, M1, S1, M2, S2, hp1p, hp2p, njt);
    combine_kernel<<<ROWS / 4, 256, 0, stream>>>(x, hp1p, hp2p, JC, g1k, g2k, gbk);
  }

  pool_kernel<<<dim3(D_, B_), 256, 0, stream>>>(x, V, pooled);
  fc_kernel<<<1, 1024, 0, stream>>>(pooled, w0, b0, w1, b1, w2, b2, w3, b3, outp);
}